// Round 5
// baseline (1567.301 us; speedup 1.0000x reference)
//
#include <hip/hip_runtime.h>
#include <stdint.h>

typedef unsigned int u32;

// ---------- Threefry-2x32/20 (JAX PRNG) ----------
__device__ __forceinline__ u32 rotl32(u32 x, int r) { return (x << r) | (x >> (32 - r)); }

__device__ __forceinline__ uint2 threefry2x32(u32 k0, u32 k1, u32 x0, u32 x1) {
  u32 ks2 = k0 ^ k1 ^ 0x1BD11BDAu;
  x0 += k0; x1 += k1;
#define TF_G(a,b,c,d) { x0 += x1; x1 = rotl32(x1,a); x1 ^= x0; \
                        x0 += x1; x1 = rotl32(x1,b); x1 ^= x0; \
                        x0 += x1; x1 = rotl32(x1,c); x1 ^= x0; \
                        x0 += x1; x1 = rotl32(x1,d); x1 ^= x0; }
  TF_G(13,15,26,6);  x0 += k1;  x1 += ks2 + 1u;
  TF_G(17,29,16,24); x0 += ks2; x1 += k0  + 2u;
  TF_G(13,15,26,6);  x0 += k0;  x1 += k1  + 3u;
  TF_G(17,29,16,24); x0 += k1;  x1 += ks2 + 4u;
  TF_G(13,15,26,6);  x0 += ks2; x1 += k0  + 5u;
#undef TF_G
  return make_uint2(x0, x1);
}

// ======================================================================
// Kernel 1: 4 modality branches -> proj (f32) written to out[b][s][o]
// grid (8 o-tiles, 4 modalities, 256 batch), block 256
// ======================================================================
__global__ __launch_bounds__(256) void branch_kernel(
    const float* __restrict__ x0p, const float* __restrict__ x1p,
    const float* __restrict__ x2p, const float* __restrict__ x3p,
    const float* __restrict__ conv_w, const float* __restrict__ conv_b,
    const float* __restrict__ bn_g, const float* __restrict__ bn_b,
    const float* __restrict__ bn_m, const float* __restrict__ bn_v,
    const float* __restrict__ lin_w_img, const float* __restrict__ lin_b_img,
    const float* __restrict__ lin_w_pc, const float* __restrict__ lin_b_pc,
    float* __restrict__ out)
{
  __shared__ float Xs[49][68];   // L x 64 k-chunk
  __shared__ float Ws[64][68];   // 64 o x 64 k-chunk
  __shared__ float hs[64][53];   // BN+relu'd conv output [o][l]
  __shared__ float lws[32 * 49];
  __shared__ float lbs[32];
  __shared__ float bnA[64], bnC[64];

  const int ot  = blockIdx.x;   // o tile (64 wide)
  const int mod = blockIdx.y;   // 0 rgb, 1 depth, 2 mmwave, 3 lidar
  const int b   = blockIdx.z;
  const int tid = threadIdx.x;
  const int L   = (mod < 2) ? 49 : 32;
  const float* xp = (mod == 0) ? x0p : (mod == 1) ? x1p : (mod == 2) ? x2p : x3p;
  const float* lw = (mod < 2) ? (lin_w_img + mod * 32 * 49) : (lin_w_pc + (mod - 2) * 32 * 32);
  const float* lb = (mod < 2) ? (lin_b_img + mod * 32)      : (lin_b_pc + (mod - 2) * 32);

  for (int i = tid; i < 32 * L; i += 256) lws[i] = lw[i];
  if (tid < 32) lbs[tid] = lb[tid];
  if (tid < 64) {
    int o = mod * 512 + ot * 64 + tid;
    float sc = bn_g[o] / sqrtf(bn_v[o] + 1e-5f);
    bnA[tid] = sc;
    bnC[tid] = (conv_b[o] - bn_m[o]) * sc + bn_b[o];
  }

  float acc[4][4];
#pragma unroll
  for (int i = 0; i < 4; i++)
#pragma unroll
    for (int j = 0; j < 4; j++) acc[i][j] = 0.f;

  const int tx = tid & 15, ty = tid >> 4;
  const int nl = (L - ty + 15) >> 4;   // valid l-slots: l = ty + 16*li

  for (int k0 = 0; k0 < 512; k0 += 64) {
    for (int i = tid; i < L * 16; i += 256) {
      int l = i >> 4, j = i & 15;
      float4 v = *(const float4*)(xp + (size_t)(b * L + l) * 512 + k0 + j * 4);
      *(float4*)&Xs[l][j * 4] = v;
    }
    for (int i = tid; i < 64 * 16; i += 256) {
      int o = i >> 4, j = i & 15;
      float4 v = *(const float4*)(conv_w + (size_t)(mod * 512 + ot * 64 + o) * 512 + k0 + j * 4);
      *(float4*)&Ws[o][j * 4] = v;
    }
    __syncthreads();
#pragma unroll 4
    for (int kk = 0; kk < 64; kk += 4) {
      float4 wv[4];
#pragma unroll
      for (int j = 0; j < 4; j++) wv[j] = *(const float4*)&Ws[tx + 16 * j][kk];
      for (int li = 0; li < nl; li++) {
        float4 xv = *(const float4*)&Xs[ty + 16 * li][kk];
#pragma unroll
        for (int j = 0; j < 4; j++) {
          acc[li][j] = fmaf(xv.x, wv[j].x, acc[li][j]);
          acc[li][j] = fmaf(xv.y, wv[j].y, acc[li][j]);
          acc[li][j] = fmaf(xv.z, wv[j].z, acc[li][j]);
          acc[li][j] = fmaf(xv.w, wv[j].w, acc[li][j]);
        }
      }
    }
    __syncthreads();
  }

  // BN + ReLU -> hs[o][l]
  for (int li = 0; li < nl; li++) {
    int l = ty + 16 * li;
#pragma unroll
    for (int j = 0; j < 4; j++) {
      int o = tx + 16 * j;
      float v = acc[li][j] * bnA[o] + bnC[o];
      hs[o][l] = v > 0.f ? v : 0.f;
    }
  }
  __syncthreads();

  // stage B: relu(sum_l hs[o][l]*lw[kk][l] + lb[kk]) -> out[b][mod*32+kk][og]
  {
    int o_l = tid & 63, kg = tid >> 6;
    int og = ot * 64 + o_l;
#pragma unroll
    for (int kq = 0; kq < 8; kq++) {
      int kk = kg * 8 + kq;
      float s = lbs[kk];
      for (int l = 0; l < L; l++)
        s = fmaf(hs[o_l][l], lws[kk * L + l], s);
      s = s > 0.f ? s : 0.f;
      out[((size_t)b * 128 + mod * 32 + kk) * 512 + og] = s;
    }
  }
}

// ======================================================================
// Kernel 2: farthest point sampling, one block per batch. f32 bit-exact:
// no FMA contraction, argmax tie-break = lowest index (first occurrence).
// ======================================================================
__global__ __launch_bounds__(256) void fps_kernel(const float* __restrict__ pts,
                                                  int* __restrict__ idx_out)
{
  __shared__ float xs[4096], ys[4096], zs[4096];
  __shared__ float rv[4];
  __shared__ int   ri[4];
  __shared__ int   far_sh;
  const int b = blockIdx.x, tid = threadIdx.x;
  const float* pb = pts + (size_t)b * 4096 * 3;

  for (int i = tid; i < 12288; i += 256) {
    float v = pb[i];
    int n = i / 3, c = i - n * 3;
    float* dst = (c == 0) ? xs : (c == 1) ? ys : zs;
    dst[n] = v;
  }
  float dreg[16];
#pragma unroll
  for (int i = 0; i < 16; i++) dreg[i] = 1e10f;
  __syncthreads();

  // far0 = jax.random.randint(jax.random.key(42), (256,), 0, 4096)[b]
  // randint: k1,k2 = split(key); span=4096 -> multiplier=0 -> offset = lower_bits(k2) & 4095.
  // Partitionable (JAX >= 0.4.30 default):
  //   split (fold-like): k2 = threefry2x32((0,42), iota64=1) full output pair
  //   random_bits 32-bit at counter b: (o0 ^ o1) of threefry2x32(k2, 0, b)
  uint2 k2 = threefry2x32(0u, 42u, 0u, 1u);
  uint2 r  = threefry2x32(k2.x, k2.y, 0u, (u32)b);
  int far  = (int)((r.x ^ r.y) & 4095u);

  for (int s = 0; s < 128; s++) {
    if (tid == 0) idx_out[b * 128 + s] = far;
    float cx = xs[far], cy = ys[far], cz = zs[far];
    float bestv = -1.f; int besti = 0x7FFFFFFF;
#pragma unroll
    for (int i = 0; i < 16; i++) {
      int n = tid + (i << 8);
      float dx = __fsub_rn(xs[n], cx);
      float dy = __fsub_rn(ys[n], cy);
      float dz = __fsub_rn(zs[n], cz);
      float d  = __fadd_rn(__fadd_rn(__fmul_rn(dx, dx), __fmul_rn(dy, dy)), __fmul_rn(dz, dz));
      float nd = fminf(dreg[i], d);
      dreg[i] = nd;
      if (nd > bestv) { bestv = nd; besti = n; }   // n ascending -> ties keep first
    }
#pragma unroll
    for (int off = 1; off < 64; off <<= 1) {
      float ov = __shfl_xor(bestv, off, 64);
      int   oi = __shfl_xor(besti, off, 64);
      if (ov > bestv || (ov == bestv && oi < besti)) { bestv = ov; besti = oi; }
    }
    if ((tid & 63) == 0) { rv[tid >> 6] = bestv; ri[tid >> 6] = besti; }
    __syncthreads();
    if (tid == 0) {
      float bv = rv[0]; int bi = ri[0];
#pragma unroll
      for (int w = 1; w < 4; w++)
        if (rv[w] > bv || (rv[w] == bv && ri[w] < bi)) { bv = rv[w]; bi = ri[w]; }
      far_sh = bi;
    }
    __syncthreads();
    far = far_sh;
  }
}

// ======================================================================
// Kernel 3: pos-enc MLP (3->128->512) on gathered points; RMW-adds into out.
// grid (16 o-tiles of 32, 2 s-tiles of 64, 256 batch), block 256
// ======================================================================
__global__ __launch_bounds__(256) void pe_kernel(
    const float* __restrict__ pts, const int* __restrict__ fps_idx,
    const float* __restrict__ w1, const float* __restrict__ b1,
    const float* __restrict__ g1, const float* __restrict__ bb1,
    const float* __restrict__ m1, const float* __restrict__ v1,
    const float* __restrict__ w2, const float* __restrict__ b2,
    const float* __restrict__ g2, const float* __restrict__ bb2,
    const float* __restrict__ m2, const float* __restrict__ v2,
    float* __restrict__ out)
{
  __shared__ float h1T[64][132];   // [s_local][c]
  __shared__ float w2s[32][132];   // [o_local][c]
  const int ot = blockIdx.x;       // o tile (32 wide)
  const int st = blockIdx.y;       // s tile (64 wide)
  const int b  = blockIdx.z;
  const int tid = threadIdx.x;

  for (int i = tid; i < 32 * 32; i += 256) {
    int o = i >> 5, j = i & 31;
    float4 v = *(const float4*)(w2 + (size_t)(ot * 32 + o) * 128 + j * 4);
    *(float4*)&w2s[o][j * 4] = v;
  }
  {
    int s_l = tid & 63;
    int cq  = tid >> 6;            // c-quarter 0..3
    int s   = st * 64 + s_l;
    int n   = fps_idx[b * 128 + s];
    float px = pts[((size_t)b * 4096 + n) * 3 + 0];
    float py = pts[((size_t)b * 4096 + n) * 3 + 1];
    float pz = pts[((size_t)b * 4096 + n) * 3 + 2];
    for (int cc = 0; cc < 32; cc++) {
      int c = cq * 32 + cc;
      float sc = g1[c] / sqrtf(v1[c] + 1e-5f);
      float C  = (b1[c] - m1[c]) * sc + bb1[c];
      float d  = fmaf(pz, w1[c * 3 + 2], fmaf(py, w1[c * 3 + 1], px * w1[c * 3]));
      float h  = d * sc + C;
      h1T[s_l][c] = h > 0.f ? h : 0.f;
    }
  }
  __syncthreads();

  const int tx = tid & 15, ty = tid >> 4;
  float acc[2][4];
#pragma unroll
  for (int j = 0; j < 2; j++)
#pragma unroll
    for (int i = 0; i < 4; i++) acc[j][i] = 0.f;

  for (int c = 0; c < 128; c += 4) {
    float4 wv[2];
#pragma unroll
    for (int j = 0; j < 2; j++) wv[j] = *(const float4*)&w2s[tx + 16 * j][c];
#pragma unroll
    for (int si = 0; si < 4; si++) {
      float4 hv = *(const float4*)&h1T[ty + 16 * si][c];
#pragma unroll
      for (int j = 0; j < 2; j++) {
        acc[j][si] = fmaf(hv.x, wv[j].x, acc[j][si]);
        acc[j][si] = fmaf(hv.y, wv[j].y, acc[j][si]);
        acc[j][si] = fmaf(hv.z, wv[j].z, acc[j][si]);
        acc[j][si] = fmaf(hv.w, wv[j].w, acc[j][si]);
      }
    }
  }

#pragma unroll
  for (int j = 0; j < 2; j++) {
    int o = ot * 32 + tx + 16 * j;
    float sc = g2[o] / sqrtf(v2[o] + 1e-5f);
    float C  = (b2[o] - m2[o]) * sc + bb2[o];
#pragma unroll
    for (int si = 0; si < 4; si++) {
      int s = st * 64 + ty + 16 * si;
      float v = acc[j][si] * sc + C;
      v = v > 0.f ? v : 0.f;
      size_t oi = ((size_t)b * 128 + s) * 512 + o;
      out[oi] = out[oi] + v;
    }
  }
}

// ======================================================================
extern "C" void kernel_launch(void* const* d_in, const int* in_sizes, int n_in,
                              void* d_out, int out_size, void* d_ws, size_t ws_size,
                              hipStream_t stream) {
  const float* rgb    = (const float*)d_in[0];
  const float* depth  = (const float*)d_in[1];
  const float* mmwave = (const float*)d_in[2];
  const float* lidar  = (const float*)d_in[3];
  const float* pts    = (const float*)d_in[4];
  const float* conv_w = (const float*)d_in[5];
  const float* conv_b = (const float*)d_in[6];
  const float* bn_g   = (const float*)d_in[7];
  const float* bn_b   = (const float*)d_in[8];
  const float* bn_m   = (const float*)d_in[9];
  const float* bn_v   = (const float*)d_in[10];
  const float* lwi    = (const float*)d_in[11];
  const float* lbi    = (const float*)d_in[12];
  const float* lwp    = (const float*)d_in[13];
  const float* lbp    = (const float*)d_in[14];
  const float* pw1    = (const float*)d_in[15];
  const float* pb1    = (const float*)d_in[16];
  const float* pg1    = (const float*)d_in[17];
  const float* pbb1   = (const float*)d_in[18];
  const float* pm1    = (const float*)d_in[19];
  const float* pv1    = (const float*)d_in[20];
  const float* pw2    = (const float*)d_in[21];
  const float* pb2    = (const float*)d_in[22];
  const float* pg2    = (const float*)d_in[23];
  const float* pbb2   = (const float*)d_in[24];
  const float* pm2    = (const float*)d_in[25];
  const float* pv2    = (const float*)d_in[26];
  float* out = (float*)d_out;
  int* fps_idx = (int*)d_ws;   // 256*128*4 = 128 KB

  branch_kernel<<<dim3(8, 4, 256), 256, 0, stream>>>(rgb, depth, mmwave, lidar,
      conv_w, conv_b, bn_g, bn_b, bn_m, bn_v, lwi, lbi, lwp, lbp, out);
  fps_kernel<<<dim3(256), 256, 0, stream>>>(pts, fps_idx);
  pe_kernel<<<dim3(16, 2, 256), 256, 0, stream>>>(pts, fps_idx, pw1, pb1, pg1, pbb1, pm1, pv1,
      pw2, pb2, pg2, pbb2, pm2, pv2, out);
}

// Round 6
// 739.884 us; speedup vs baseline: 2.1183x; 2.1183x over previous
//
#include <hip/hip_runtime.h>
#include <stdint.h>

typedef unsigned int u32;
typedef unsigned short u16;

typedef __attribute__((ext_vector_type(8))) short bf16x8;
typedef __attribute__((ext_vector_type(4))) float f32x4;

// f32 -> bf16 round-to-nearest-even
__device__ __forceinline__ u16 f2bfu(float f) {
  union { float f; u32 u; } v; v.f = f;
  return (u16)((v.u + 0x7FFFu + ((v.u >> 16) & 1u)) >> 16);
}

// ---------- Threefry-2x32/20 (JAX PRNG) ----------
__device__ __forceinline__ u32 rotl32(u32 x, int r) { return (x << r) | (x >> (32 - r)); }

__device__ __forceinline__ uint2 threefry2x32(u32 k0, u32 k1, u32 x0, u32 x1) {
  u32 ks2 = k0 ^ k1 ^ 0x1BD11BDAu;
  x0 += k0; x1 += k1;
#define TF_G(a,b,c,d) { x0 += x1; x1 = rotl32(x1,a); x1 ^= x0; \
                        x0 += x1; x1 = rotl32(x1,b); x1 ^= x0; \
                        x0 += x1; x1 = rotl32(x1,c); x1 ^= x0; \
                        x0 += x1; x1 = rotl32(x1,d); x1 ^= x0; }
  TF_G(13,15,26,6);  x0 += k1;  x1 += ks2 + 1u;
  TF_G(17,29,16,24); x0 += ks2; x1 += k0  + 2u;
  TF_G(13,15,26,6);  x0 += k0;  x1 += k1  + 3u;
  TF_G(17,29,16,24); x0 += k1;  x1 += ks2 + 4u;
  TF_G(13,15,26,6);  x0 += ks2; x1 += k0  + 5u;
#undef TF_G
  return make_uint2(x0, x1);
}

// ======================================================================
// Kernel 1: branch conv(512->512)+BN+ReLU via bf16 MFMA, then fused
// Linear(L->32)+ReLU via a second small MFMA GEMM.
// grid (4 o-tiles of 128, 768 (mod,b)-slots), block 256 (4 waves).
//   img mods (rgb/depth):  1 batch/block,  C tile 128o x 64l (49 real)
//   pc  mods (mmwave/lidar): 2 batches/block, C tile 128o x 64l (2x32)
// ======================================================================
#define WB_OFF   0        // ushort [128][32]  (8192 B)
#define XB_OFF   8192     // ushort [64][32]   (4096 B)
#define CB_OFF   0        // float  [32][132]  (16896 B)  reuses Wb/Xb after K-loop
#define HS_OFF   16896    // ushort [128][88]  (22528 B)
#define LW2_OFF  39424    // ushort [32][72]   (4608 B)
#define BNA_OFF  44032    // float  [128]
#define BNC_OFF  44544    // float  [128]
#define LBS_OFF  45056    // float  [32]
#define SMEM_SZ  45184

__global__ __launch_bounds__(256) void branch_kernel(
    const float* __restrict__ x0p, const float* __restrict__ x1p,
    const float* __restrict__ x2p, const float* __restrict__ x3p,
    const float* __restrict__ conv_w, const float* __restrict__ conv_b,
    const float* __restrict__ bn_g, const float* __restrict__ bn_b,
    const float* __restrict__ bn_m, const float* __restrict__ bn_v,
    const float* __restrict__ lin_w_img, const float* __restrict__ lin_b_img,
    const float* __restrict__ lin_w_pc, const float* __restrict__ lin_b_pc,
    float* __restrict__ out)
{
  __shared__ __align__(16) char sm[SMEM_SZ];
  u16*   Wb  = (u16*)(sm + WB_OFF);
  u16*   Xb  = (u16*)(sm + XB_OFF);
  float* Cb  = (float*)(sm + CB_OFF);
  u16*   hsB = (u16*)(sm + HS_OFF);
  u16*   lw2 = (u16*)(sm + LW2_OFF);
  float* bnA = (float*)(sm + BNA_OFF);
  float* bnC = (float*)(sm + BNC_OFF);
  float* lbs = (float*)(sm + LBS_OFF);

  const int ot  = blockIdx.x;
  const int tid = threadIdx.x;
  int y = blockIdx.y;
  int mod, bidx = 0, bg = 0;
  if      (y < 256) { mod = 0; bidx = y; }
  else if (y < 512) { mod = 1; bidx = y - 256; }
  else if (y < 640) { mod = 2; bg   = y - 512; }
  else              { mod = 3; bg   = y - 640; }
  const bool img = (mod < 2);
  const int  L   = img ? 49 : 32;
  const float* xp = (mod == 0) ? x0p : (mod == 1) ? x1p : (mod == 2) ? x2p : x3p;
  const float* lw = img ? (lin_w_img + mod * 32 * 49) : (lin_w_pc + (mod - 2) * 32 * 32);
  const float* lb = img ? (lin_b_img + mod * 32)      : (lin_b_pc + (mod - 2) * 32);

  // stage small constants (read only after later barriers)
  for (int i = tid; i < 32 * 64; i += 256) {
    int kk = i >> 6, l = i & 63;
    float v = (l < L) ? lw[kk * L + l] : 0.f;   // zero-pad kills l>=L garbage
    lw2[kk * 72 + l] = f2bfu(v);
  }
  if (tid < 32) lbs[tid] = lb[tid];
  if (tid < 128) {
    int o = mod * 512 + ot * 128 + tid;
    float sc = bn_g[o] / sqrtf(bn_v[o] + 1e-5f);
    bnA[tid] = sc;
    bnC[tid] = (conv_b[o] - bn_m[o]) * sc + bn_b[o];
  }

  const int lane = tid & 63, w = tid >> 6, quad = lane >> 4, lm = lane & 15;
  const float* wbase = conv_w + (size_t)(mod * 512 + ot * 128) * 512;

  f32x4 acc[2][4];
#pragma unroll
  for (int mi = 0; mi < 2; mi++)
#pragma unroll
    for (int nt = 0; nt < 4; nt++) acc[mi][nt] = (f32x4){0.f, 0.f, 0.f, 0.f};

  // ---- stage A: C[128 o][64 l] = W @ X^T over K=512, 16 k-steps of 32 ----
  for (int ks = 0; ks < 16; ks++) {
    int k0 = ks * 32;
    __syncthreads();
    for (int i = tid; i < 1024; i += 256) {           // Wb: 128 rows x 8 segs
      int row = i >> 3, seg = i & 7;
      float4 v = *(const float4*)(wbase + (size_t)row * 512 + k0 + seg * 4);
      u16* d = &Wb[row * 32 + seg * 4];
      d[0] = f2bfu(v.x); d[1] = f2bfu(v.y); d[2] = f2bfu(v.z); d[3] = f2bfu(v.w);
    }
    for (int i = tid; i < 512; i += 256) {            // Xb: 64 rows x 8 segs
      int l = i >> 3, seg = i & 7;
      float4 v = make_float4(0.f, 0.f, 0.f, 0.f);
      if (img) {
        if (l < 49) v = *(const float4*)(xp + (size_t)(bidx * 49 + l) * 512 + k0 + seg * 4);
      } else {
        v = *(const float4*)(xp + (size_t)(bg * 64 + l) * 512 + k0 + seg * 4);
      }
      u16* d = &Xb[l * 32 + seg * 4];
      d[0] = f2bfu(v.x); d[1] = f2bfu(v.y); d[2] = f2bfu(v.z); d[3] = f2bfu(v.w);
    }
    __syncthreads();
    bf16x8 af[2], bfr[4];
#pragma unroll
    for (int mi = 0; mi < 2; mi++)
      af[mi] = *(const bf16x8*)&Wb[(w * 32 + mi * 16 + lm) * 32 + quad * 8];
#pragma unroll
    for (int nt = 0; nt < 4; nt++)
      bfr[nt] = *(const bf16x8*)&Xb[(nt * 16 + lm) * 32 + quad * 8];
#pragma unroll
    for (int mi = 0; mi < 2; mi++)
#pragma unroll
      for (int nt = 0; nt < 4; nt++)
        acc[mi][nt] = __builtin_amdgcn_mfma_f32_16x16x32_bf16(af[mi], bfr[nt], acc[mi][nt], 0, 0, 0);
  }
  __syncthreads();

  // ---- BN + ReLU -> hs (bf16), C/D layout: col=lane&15, row=quad*4+reg ----
#pragma unroll
  for (int mi = 0; mi < 2; mi++)
#pragma unroll
    for (int nt = 0; nt < 4; nt++)
#pragma unroll
      for (int r = 0; r < 4; r++) {
        int o_loc = w * 32 + mi * 16 + quad * 4 + r;
        int l     = nt * 16 + lm;
        float v = acc[mi][nt][r] * bnA[o_loc] + bnC[o_loc];
        hsB[o_loc * 88 + l] = f2bfu(v > 0.f ? v : 0.f);
      }
  __syncthreads();

  // ---- stage B: out[b][mod*32+kk][o] = relu(hs @ lw^T + lb), via MFMA ----
  const int npass = img ? 1 : 2;
  const int nkt   = img ? 2 : 1;
  for (int p = 0; p < npass; p++) {
    f32x4 c2[2][2];
#pragma unroll
    for (int mi = 0; mi < 2; mi++)
#pragma unroll
      for (int nt2 = 0; nt2 < 2; nt2++) c2[mi][nt2] = (f32x4){0.f, 0.f, 0.f, 0.f};
    for (int kt = 0; kt < nkt; kt++) {
      int aoff = img ? kt * 32 : p * 32;
      int boff = img ? kt * 32 : 0;
      bf16x8 a2[2], b2[2];
#pragma unroll
      for (int mi = 0; mi < 2; mi++)
        a2[mi] = *(const bf16x8*)&hsB[(w * 32 + mi * 16 + lm) * 88 + aoff + quad * 8];
#pragma unroll
      for (int nt2 = 0; nt2 < 2; nt2++)
        b2[nt2] = *(const bf16x8*)&lw2[(nt2 * 16 + lm) * 72 + boff + quad * 8];
#pragma unroll
      for (int mi = 0; mi < 2; mi++)
#pragma unroll
        for (int nt2 = 0; nt2 < 2; nt2++)
          c2[mi][nt2] = __builtin_amdgcn_mfma_f32_16x16x32_bf16(a2[mi], b2[nt2], c2[mi][nt2], 0, 0, 0);
    }
#pragma unroll
    for (int mi = 0; mi < 2; mi++)
#pragma unroll
      for (int nt2 = 0; nt2 < 2; nt2++)
#pragma unroll
        for (int r = 0; r < 4; r++) {
          int kk    = nt2 * 16 + lm;
          int o_loc = w * 32 + mi * 16 + quad * 4 + r;
          float v = c2[mi][nt2][r] + lbs[kk];
          Cb[kk * 132 + o_loc] = v > 0.f ? v : 0.f;
        }
    __syncthreads();
    int b_out = img ? bidx : (bg * 2 + p);
    for (int i = tid; i < 4096; i += 256) {
      int kk = i >> 7, j = i & 127;
      out[((size_t)b_out * 128 + mod * 32 + kk) * 512 + ot * 128 + j] = Cb[kk * 132 + j];
    }
    if (p + 1 < npass) __syncthreads();
  }
}

// ======================================================================
// Kernel 2: farthest point sampling (unchanged from round 5 — bit-exact)
// ======================================================================
__global__ __launch_bounds__(256) void fps_kernel(const float* __restrict__ pts,
                                                  int* __restrict__ idx_out)
{
  __shared__ float xs[4096], ys[4096], zs[4096];
  __shared__ float rv[4];
  __shared__ int   ri[4];
  __shared__ int   far_sh;
  const int b = blockIdx.x, tid = threadIdx.x;
  const float* pb = pts + (size_t)b * 4096 * 3;

  for (int i = tid; i < 12288; i += 256) {
    float v = pb[i];
    int n = i / 3, c = i - n * 3;
    float* dst = (c == 0) ? xs : (c == 1) ? ys : zs;
    dst[n] = v;
  }
  float dreg[16];
#pragma unroll
  for (int i = 0; i < 16; i++) dreg[i] = 1e10f;
  __syncthreads();

  // far0: randint -> k1,k2=split(key); span 4096 pow2 -> lower_bits(k2)&4095
  uint2 k2 = threefry2x32(0u, 42u, 0u, 1u);
  uint2 r  = threefry2x32(k2.x, k2.y, 0u, (u32)b);
  int far  = (int)((r.x ^ r.y) & 4095u);

  for (int s = 0; s < 128; s++) {
    if (tid == 0) idx_out[b * 128 + s] = far;
    float cx = xs[far], cy = ys[far], cz = zs[far];
    float bestv = -1.f; int besti = 0x7FFFFFFF;
#pragma unroll
    for (int i = 0; i < 16; i++) {
      int n = tid + (i << 8);
      float dx = __fsub_rn(xs[n], cx);
      float dy = __fsub_rn(ys[n], cy);
      float dz = __fsub_rn(zs[n], cz);
      float d  = __fadd_rn(__fadd_rn(__fmul_rn(dx, dx), __fmul_rn(dy, dy)), __fmul_rn(dz, dz));
      float nd = fminf(dreg[i], d);
      dreg[i] = nd;
      if (nd > bestv) { bestv = nd; besti = n; }
    }
#pragma unroll
    for (int off = 1; off < 64; off <<= 1) {
      float ov = __shfl_xor(bestv, off, 64);
      int   oi = __shfl_xor(besti, off, 64);
      if (ov > bestv || (ov == bestv && oi < besti)) { bestv = ov; besti = oi; }
    }
    if ((tid & 63) == 0) { rv[tid >> 6] = bestv; ri[tid >> 6] = besti; }
    __syncthreads();
    if (tid == 0) {
      float bv = rv[0]; int bi = ri[0];
#pragma unroll
      for (int w = 1; w < 4; w++)
        if (rv[w] > bv || (rv[w] == bv && ri[w] < bi)) { bv = rv[w]; bi = ri[w]; }
      far_sh = bi;
    }
    __syncthreads();
    far = far_sh;
  }
}

// ======================================================================
// Kernel 3: pos-enc MLP (unchanged from round 5)
// ======================================================================
__global__ __launch_bounds__(256) void pe_kernel(
    const float* __restrict__ pts, const int* __restrict__ fps_idx,
    const float* __restrict__ w1, const float* __restrict__ b1,
    const float* __restrict__ g1, const float* __restrict__ bb1,
    const float* __restrict__ m1, const float* __restrict__ v1,
    const float* __restrict__ w2, const float* __restrict__ b2,
    const float* __restrict__ g2, const float* __restrict__ bb2,
    const float* __restrict__ m2, const float* __restrict__ v2,
    float* __restrict__ out)
{
  __shared__ float h1T[64][132];   // [s_local][c]
  __shared__ float w2s[32][132];   // [o_local][c]
  const int ot = blockIdx.x;       // o tile (32 wide)
  const int st = blockIdx.y;       // s tile (64 wide)
  const int b  = blockIdx.z;
  const int tid = threadIdx.x;

  for (int i = tid; i < 32 * 32; i += 256) {
    int o = i >> 5, j = i & 31;
    float4 v = *(const float4*)(w2 + (size_t)(ot * 32 + o) * 128 + j * 4);
    *(float4*)&w2s[o][j * 4] = v;
  }
  {
    int s_l = tid & 63;
    int cq  = tid >> 6;
    int s   = st * 64 + s_l;
    int n   = fps_idx[b * 128 + s];
    float px = pts[((size_t)b * 4096 + n) * 3 + 0];
    float py = pts[((size_t)b * 4096 + n) * 3 + 1];
    float pz = pts[((size_t)b * 4096 + n) * 3 + 2];
    for (int cc = 0; cc < 32; cc++) {
      int c = cq * 32 + cc;
      float sc = g1[c] / sqrtf(v1[c] + 1e-5f);
      float C  = (b1[c] - m1[c]) * sc + bb1[c];
      float d  = fmaf(pz, w1[c * 3 + 2], fmaf(py, w1[c * 3 + 1], px * w1[c * 3]));
      float h  = d * sc + C;
      h1T[s_l][c] = h > 0.f ? h : 0.f;
    }
  }
  __syncthreads();

  const int tx = tid & 15, ty = tid >> 4;
  float acc[2][4];
#pragma unroll
  for (int j = 0; j < 2; j++)
#pragma unroll
    for (int i = 0; i < 4; i++) acc[j][i] = 0.f;

  for (int c = 0; c < 128; c += 4) {
    float4 wv[2];
#pragma unroll
    for (int j = 0; j < 2; j++) wv[j] = *(const float4*)&w2s[tx + 16 * j][c];
#pragma unroll
    for (int si = 0; si < 4; si++) {
      float4 hv = *(const float4*)&h1T[ty + 16 * si][c];
#pragma unroll
      for (int j = 0; j < 2; j++) {
        acc[j][si] = fmaf(hv.x, wv[j].x, acc[j][si]);
        acc[j][si] = fmaf(hv.y, wv[j].y, acc[j][si]);
        acc[j][si] = fmaf(hv.z, wv[j].z, acc[j][si]);
        acc[j][si] = fmaf(hv.w, wv[j].w, acc[j][si]);
      }
    }
  }

#pragma unroll
  for (int j = 0; j < 2; j++) {
    int o = ot * 32 + tx + 16 * j;
    float sc = g2[o] / sqrtf(v2[o] + 1e-5f);
    float C  = (b2[o] - m2[o]) * sc + bb2[o];
#pragma unroll
    for (int si = 0; si < 4; si++) {
      int s = st * 64 + ty + 16 * si;
      float v = acc[j][si] * sc + C;
      v = v > 0.f ? v : 0.f;
      size_t oi = ((size_t)b * 128 + s) * 512 + o;
      out[oi] = out[oi] + v;
    }
  }
}

// ======================================================================
extern "C" void kernel_launch(void* const* d_in, const int* in_sizes, int n_in,
                              void* d_out, int out_size, void* d_ws, size_t ws_size,
                              hipStream_t stream) {
  const float* rgb    = (const float*)d_in[0];
  const float* depth  = (const float*)d_in[1];
  const float* mmwave = (const float*)d_in[2];
  const float* lidar  = (const float*)d_in[3];
  const float* pts    = (const float*)d_in[4];
  const float* conv_w = (const float*)d_in[5];
  const float* conv_b = (const float*)d_in[6];
  const float* bn_g   = (const float*)d_in[7];
  const float* bn_b   = (const float*)d_in[8];
  const float* bn_m   = (const float*)d_in[9];
  const float* bn_v   = (const float*)d_in[10];
  const float* lwi    = (const float*)d_in[11];
  const float* lbi    = (const float*)d_in[12];
  const float* lwp    = (const float*)d_in[13];
  const float* lbp    = (const float*)d_in[14];
  const float* pw1    = (const float*)d_in[15];
  const float* pb1    = (const float*)d_in[16];
  const float* pg1    = (const float*)d_in[17];
  const float* pbb1   = (const float*)d_in[18];
  const float* pm1    = (const float*)d_in[19];
  const float* pv1    = (const float*)d_in[20];
  const float* pw2    = (const float*)d_in[21];
  const float* pb2    = (const float*)d_in[22];
  const float* pg2    = (const float*)d_in[23];
  const float* pbb2   = (const float*)d_in[24];
  const float* pm2    = (const float*)d_in[25];
  const float* pv2    = (const float*)d_in[26];
  float* out = (float*)d_out;
  int* fps_idx = (int*)d_ws;   // 128 KB

  branch_kernel<<<dim3(4, 768), 256, 0, stream>>>(rgb, depth, mmwave, lidar,
      conv_w, conv_b, bn_g, bn_b, bn_m, bn_v, lwi, lbi, lwp, lbp, out);
  fps_kernel<<<dim3(256), 256, 0, stream>>>(pts, fps_idx);
  pe_kernel<<<dim3(16, 2, 256), 256, 0, stream>>>(pts, fps_idx, pw1, pb1, pg1, pbb1, pm1, pv1,
      pw2, pb2, pg2, pbb2, pm2, pv2, out);
}